// Round 14
// baseline (268.689 us; speedup 1.0000x reference)
//
#include <hip/hip_runtime.h>
#include <hip/hip_bf16.h>

typedef unsigned short u16;
typedef unsigned int u32;
typedef short short8 __attribute__((ext_vector_type(8)));
typedef unsigned short ushort4v __attribute__((ext_vector_type(4)));
typedef float f32x4 __attribute__((ext_vector_type(4)));
typedef float f32x16 __attribute__((ext_vector_type(16)));
typedef u32 u32x4 __attribute__((ext_vector_type(4)));

#define SEQN 4096
#define HID 2048
#define NH 16
#define NKV 4
#define HD 128
#define QDIM 2048   // NH*HD
#define KVD 512     // NKV*HD
#define QKVS 3072   // fused QKV row stride

static __device__ __forceinline__ float bf2f(u16 u){
  unsigned x = ((unsigned)u) << 16; float f; __builtin_memcpy(&f, &x, 4); return f;
}
static __device__ __forceinline__ u16 f2bf(float f){
  unsigned x; __builtin_memcpy(&x, &f, 4);
  x += 0x7fffu + ((x >> 16) & 1u);
  return (u16)(x >> 16);
}
// cheap round-half-up bf16 (<=1 ulp vs RNE)
static __device__ __forceinline__ u16 f2bfc(float f){
  unsigned x; __builtin_memcpy(&x, &f, 4);
  return (u16)((x + 0x8000u) >> 16);
}
// cheap packed pair: low16 = bf16(a), high16 = bf16(b)
static __device__ __forceinline__ u32 pkr(float a, float b){
  u32 ab, bb; __builtin_memcpy(&ab, &a, 4); __builtin_memcpy(&bb, &b, 4);
  return ((ab + 0x8000u) >> 16) | ((bb + 0x8000u) & 0xffff0000u);
}

// ---------------- fused fp32 -> bf16 convert (all 5 inputs, one launch) ----------------
#define G1 (SEQN*HID/4)
#define G2 (QDIM*HID/4)
#define G3 (KVD*HID/4)
#define G4 (KVD*HID/4)
#define G5 (HID*QDIM/4)
__global__ __launch_bounds__(256) void cvt5_kernel(const float* __restrict__ x,  const float* __restrict__ Wq,
                                                   const float* __restrict__ Wk, const float* __restrict__ Wv,
                                                   const float* __restrict__ Wo, u16* __restrict__ xb,
                                                   u16* __restrict__ Wqkvb, u16* __restrict__ Wob){
  int g = blockIdx.x * 256 + threadIdx.x;
  const float* src; u16* dst; int off;
  if (g < G1)                { src = x;  dst = xb;    off = g; }
  else if (g < G1+G2)        { src = Wq; dst = Wqkvb; off = g - G1; }
  else if (g < G1+G2+G3)     { src = Wk; dst = Wqkvb + (size_t)QDIM*HID;        off = g - (G1+G2); }
  else if (g < G1+G2+G3+G4)  { src = Wv; dst = Wqkvb + (size_t)(QDIM+KVD)*HID;  off = g - (G1+G2+G3); }
  else if (g < G1+G2+G3+G4+G5){ src = Wo; dst = Wob;  off = g - (G1+G2+G3+G4); }
  else return;
  f32x4 v = ((const f32x4*)src)[off];
  ushort4v o;
  o.x = f2bf(v.x); o.y = f2bf(v.y); o.z = f2bf(v.z); o.w = f2bf(v.w);
  ((ushort4v*)dst)[off] = o;
}

// ---------------- fused RoPE (Q,K) + V transpose, one launch ----------------
#define ROPE_BLKS (SEQN * (NH + NKV) * 16 / 256)     // 5120
__global__ __launch_bounds__(256) void prep_kernel(u16* __restrict__ QKVb, u16* __restrict__ VTg){
  __shared__ u16 T[64][72];
  const int bid = blockIdx.x;
  const int tid = threadIdx.x;
  if (bid < ROPE_BLKS){
    int idx = bid * 256 + tid;                 // one thread = 8 elems (4 pairs)
    int i8 = idx & 15;
    int rest = idx >> 4;
    int h = rest % (NH + NKV);
    int s = rest / (NH + NKV);
    int col = (h < NH) ? h * HD : QDIM + (h - NH) * HD;
    u16* p = QKVb + (size_t)s * QKVS + col + i8 * 8;
    short8 v = *(const short8*)p;
    short8 o;
#pragma unroll
    for (int j = 0; j < 4; j++){
      int i = i8 * 4 + j;
      float freq = expf(-0.14391156831212788f * (float)i);
      float ang = (float)s * freq;
      float c = cosf(ang), sn = sinf(ang);
      float x1 = bf2f((u16)v[2*j]), x2 = bf2f((u16)v[2*j+1]);
      o[2*j]   = (short)f2bfc(x1 * c - x2 * sn);
      o[2*j+1] = (short)f2bfc(x1 * sn + x2 * c);
    }
    *(short8*)p = o;
  } else {
    const int b2 = bid - ROPE_BLKS;
    const int s0 = (b2 & 63) * 64;
    const int c0 = (b2 >> 6) * 64;
    const int sl = tid & 63, ch = tid >> 6;
    const u16* src = QKVb + QDIM + KVD + (size_t)(s0 + sl) * QKVS + c0 + ch * 16;
    *(short8*)&T[sl][ch * 16]     = *(const short8*)(src);
    *(short8*)&T[sl][ch * 16 + 8] = *(const short8*)(src + 8);
    __syncthreads();
#pragma unroll
    for (int it = 0; it < 16; it++){
      int c = it * 4 + ch;
      VTg[(size_t)(c0 + c) * SEQN + s0 + sl] = T[sl][c];
    }
  }
}

// ---------------- async global->LDS 16B ----------------
static __device__ __forceinline__ void gload16(const void* g, void* l){
  __builtin_amdgcn_global_load_lds((const __attribute__((address_space(1))) void*)g,
                                   (__attribute__((address_space(3))) void*)l, 16, 0, 0);
}

// ---------------- GEMM: C[M][N(ldc)] = A[M][K] * B[N][K]^T ----------------
template<int F32OUT>
__global__ __launch_bounds__(256) void gemm_kernel(const u16* __restrict__ A, const u16* __restrict__ B,
                                                   void* __restrict__ Cout, int M, int N, int Kd, int ldc){
  __shared__ alignas(16) u16 sh[8192];          // As = sh[0..4096), Bs = sh[4096..8192)
  u16* As = sh;
  u16* Bs = sh + 4096;
  const int tid = threadIdx.x;
  const int w = tid >> 6, l = tid & 63;
  const int wr = w >> 1, wc = w & 1;
  const int lc = l & 15, lg = l >> 4;
  const int tm = blockIdx.x * 128, tn = blockIdx.y * 128;

  const int srow = w * 32 + (l >> 2);
  const int scol = (l & 3) * 8;
  const u16* Ag = A + (size_t)(tm + srow) * Kd + scol;
  const u16* Bg = B + (size_t)(tn + srow) * Kd + scol;
  u16* As0 = As + (w * 2) * 512;
  u16* Bs0 = Bs + (w * 2) * 512;

  f32x4 acc[4][4] = {};

  for (int k0 = 0; k0 < Kd; k0 += 32){
    gload16(Ag + k0,                    As0);
    gload16(Ag + k0 + (size_t)16 * Kd,  As0 + 512);
    gload16(Bg + k0,                    Bs0);
    gload16(Bg + k0 + (size_t)16 * Kd,  Bs0 + 512);
    __syncthreads();
    short8 a[4], b[4];
#pragma unroll
    for (int mi = 0; mi < 4; mi++) a[mi] = *(const short8*)&As[(wr*64 + mi*16 + lc) * 32 + lg*8];
#pragma unroll
    for (int ni = 0; ni < 4; ni++) b[ni] = *(const short8*)&Bs[(wc*64 + ni*16 + lc) * 32 + lg*8];
#pragma unroll
    for (int mi = 0; mi < 4; mi++)
#pragma unroll
      for (int ni = 0; ni < 4; ni++)
        acc[mi][ni] = __builtin_amdgcn_mfma_f32_16x16x32_bf16(a[mi], b[ni], acc[mi][ni], 0, 0, 0);
    __syncthreads();
  }

  if (F32OUT){
#pragma unroll
    for (int mi = 0; mi < 4; mi++)
#pragma unroll
      for (int ni = 0; ni < 4; ni++)
#pragma unroll
        for (int r = 0; r < 4; r++){
          int row = tm + wr*64 + mi*16 + lg*4 + r;
          int col = tn + wc*64 + ni*16 + lc;
          ((float*)Cout)[(size_t)row * ldc + col] = acc[mi][ni][r];
        }
  } else {
    __syncthreads();
    u16* Ew = sh + w * 1168;               // [16][73] u16 per wave
#pragma unroll
    for (int mi = 0; mi < 4; mi++){
#pragma unroll
      for (int ni = 0; ni < 4; ni++)
#pragma unroll
        for (int r = 0; r < 4; r++)
          Ew[(lg * 4 + r) * 73 + ni * 16 + lc] = f2bfc(acc[mi][ni][r]);
#pragma unroll
      for (int pass = 0; pass < 2; pass++){
        int row = pass * 8 + (l >> 3);
        short8 v;
#pragma unroll
        for (int j = 0; j < 8; j++) v[j] = (short)Ew[row * 73 + (l & 7) * 8 + j];
        *(short8*)((u16*)Cout + (size_t)(tm + wr*64 + mi*16 + row) * ldc + tn + wc*64 + (l & 7) * 8) = v;
      }
    }
  }
}

// ---------------- Flash attention (causal, GQA), KVBLK=32, 3 blocks/CU target ----------------
// Grid (16, NH, 2), 256 threads, launch_bounds(256,3). KV tile 32 double-buffered:
// staging 32KB + epilogue headroom -> pool 34KB -> 3 blocks/CU (104KB LDS). Register
// diet: Sv 16 AGPR (single f32x16), staging offsets as u32. Work split: pair
// (qlo=pr, qhi=31-pr) = 132 32-tiles; s=0: qlo full (4pr+4, FINAL) + first 62-4pr of
// qhi (PARTIAL0); s=1: last 66 of qhi (PARTIAL1) -> uniform 66 staged tiles/block.
// K LDS [32][128] 4-bit chunk-XOR; V [128][32] 2-bit chunk-XOR (pre-transposed global).
// Swapped QK^T/PV, per-lane softmax, P in registers via shfl_xor(32) half-exchange.
__global__ __launch_bounds__(256, 3) void attn_kernel(const u16* __restrict__ Qg, const u16* __restrict__ Kgb,
                                                      const u16* __restrict__ VTg, u16* __restrict__ Aout,
                                                      u16* __restrict__ PO, float* __restrict__ mP,
                                                      float* __restrict__ LP){
  __shared__ alignas(16) char pool[34816];   // staging: 2 x (Ks 8KB + VT 8KB) = 32KB; epilogue 34KB

  const int pr  = blockIdx.x;            // 0..15
  const int h   = blockIdx.y;
  const int s   = blockIdx.z;
  const int kvh = h >> 2;
  const int tid = threadIdx.x;
  const int w = tid >> 6, l = tid & 63;
  const int q5 = l & 31;
  const int hi = l >> 5;
  const int hi4 = hi * 4;
  const float csc = 0.12751743f;         // (1/sqrt(128)) * log2(e)

  // staging source offsets (u32 bytes), pre-swizzled for linear-LDS global_load_lds
  u32 Koff[2], Voff[2];
#pragma unroll
  for (int i = 0; i < 2; i++){
    int blk = w * 2 + i;
    int row = blk * 4 + (l >> 4);              // K tile row 0..31
    int cg  = (l & 15) ^ (row & 15);
    Koff[i] = (u32)((row * QKVS + kvh * HD + cg * 8) * 2);
    int d   = blk * 16 + (l >> 2);             // V d-row 0..127
    int cv  = (l & 3) ^ (d & 3);
    Voff[i] = (u32)(((kvh * 128 + d) * SEQN + cv * 8) * 2);
  }

  auto issueTile = [&](int b, int kv0){
    char* Ksb = pool + b * 16384;
    char* VTb = Ksb + 8192;
#pragma unroll
    for (int i = 0; i < 2; i++)
      gload16((const char*)Kgb + (size_t)Koff[i] + (size_t)kv0 * (QKVS * 2), Ksb + (w * 2 + i) * 1024);
#pragma unroll
    for (int i = 0; i < 2; i++)
      gload16((const char*)VTg + (size_t)Voff[i] + (size_t)kv0 * 2, VTb + (w * 2 + i) * 1024);
  };

  // segment descriptors (32-granular tiles)
  const int qlo = pr, qhi = 31 - pr;
  int nseg, sq[2], st0[2], st1[2], smode[2];   // mode: 0 final, 1 partial0, 2 partial1
  if (s == 0){
    nseg = 2;
    sq[0] = qlo; st0[0] = 0;            st1[0] = 4 * pr + 4;    smode[0] = 0;
    sq[1] = qhi; st0[1] = 0;            st1[1] = 62 - 4 * pr;   smode[1] = 1;
  } else {
    nseg = 1;
    sq[0] = qhi; st0[0] = 62 - 4 * pr;  st1[0] = 128 - 4 * pr;  smode[0] = 2;
  }

  for (int sg = 0; sg < nseg; sg++){
    const int qt = sq[sg], t0 = st0[sg], t1 = st1[sg], mode = smode[sg];
    const int qbase = qt * 128 + w * 32;
    const int qa    = qbase + q5;

    short8 qf[8];
    {
      const u16* qp = Qg + (size_t)(qbase + q5) * QKVS + h * HD + hi * 8;
#pragma unroll
      for (int k0 = 0; k0 < 8; k0++) qf[k0] = *(const short8*)(qp + k0 * 16);
    }

    f32x16 Ov[4] = {};
    float Lrow = 0.f;
    float ms = -1e30f;

    auto computeTile = [&](int b, int kv0){
      if (kv0 > qbase + 31) return;
      char* Ksb = pool + b * 16384;
      char* VTb = Ksb + 8192;
      f32x16 Sv = {};
#pragma unroll
      for (int k0 = 0; k0 < 8; k0++){
        short8 kf = *(const short8*)(Ksb + q5 * 256 + (((k0 * 2 + hi) ^ (q5 & 15)) << 4));
        Sv = __builtin_amdgcn_mfma_f32_32x32x16_bf16(kf, qf[k0], Sv, 0, 0, 0);
      }
      if (kv0 + 31 > qbase){
#pragma unroll
        for (int r = 0; r < 16; r++){
          int kva = kv0 + (r & 3) + 8 * (r >> 2) + hi4;
          if (kva > qa) Sv[r] = -1e30f;
        }
      }
      float tm = fmaxf(Sv[0], Sv[1]);
#pragma unroll
      for (int r = 2; r < 16; r += 2)
        tm = fmaxf(tm, fmaxf(Sv[r], Sv[r + 1]));
      tm = fmaxf(tm, __shfl_xor(tm, 32));
      float tms = tm * csc;
      if (!__all(tms - ms <= 8.f)){
        float nms = fmaxf(ms, tms);
        float al = __builtin_amdgcn_exp2f(ms - nms);
        ms = nms;
        Lrow *= al;
#pragma unroll
        for (int nb = 0; nb < 4; nb++)
#pragma unroll
          for (int r = 0; r < 16; r++) Ov[nb][r] *= al;
      }
      float ts0 = 0.f, ts1 = 0.f;
#pragma unroll
      for (int r = 0; r < 16; r += 2){
        float p0 = __builtin_amdgcn_exp2f(__builtin_fmaf(Sv[r],     csc, -ms));
        float p1 = __builtin_amdgcn_exp2f(__builtin_fmaf(Sv[r + 1], csc, -ms));
        Sv[r] = p0; Sv[r + 1] = p1;
        ts0 += p0; ts1 += p1;
      }
      float ts = ts0 + ts1;
      ts += __shfl_xor(ts, 32);
      Lrow += ts;
#pragma unroll
      for (int kc = 0; kc < 2; kc++){
        const int rb = kc * 8;
        u32 Aw = pkr(Sv[rb + 0], Sv[rb + 1]);
        u32 Bw = pkr(Sv[rb + 2], Sv[rb + 3]);
        u32 Cw = pkr(Sv[rb + 4], Sv[rb + 5]);
        u32 Dw = pkr(Sv[rb + 6], Sv[rb + 7]);
        u32 sAw = __shfl_xor(Aw, 32);
        u32 sBw = __shfl_xor(Bw, 32);
        u32 sCw = __shfl_xor(Cw, 32);
        u32 sDw = __shfl_xor(Dw, 32);
        u32 w0 = hi ? sCw : Aw;
        u32 w1 = hi ? sDw : Bw;
        u32 w2 = hi ? Cw : sAw;
        u32 w3 = hi ? Dw : sBw;
        u32x4 pw4 = {w0, w1, w2, w3};
        short8 pf = *(short8*)&pw4;
#pragma unroll
        for (int nbd = 0; nbd < 4; nbd++){
          int drow = nbd * 32 + q5;
          short8 vf = *(const short8*)(VTb + drow * 64 + (((kc * 2 + hi) ^ (drow & 3)) << 4));
          Ov[nbd] = __builtin_amdgcn_mfma_f32_32x32x16_bf16(vf, pf, Ov[nbd], 0, 0, 0);
        }
      }
    };

    __syncthreads();                 // prior segment's pool reads done
    issueTile(0, t0 * 32);
    __syncthreads();                 // buf0 landed
    int cur = 0;
    for (int t = t0; t < t1; t++){
      if (t + 1 < t1) issueTile(cur ^ 1, (t + 1) * 32);
      computeTile(cur, t * 32);
      __syncthreads();
      cur ^= 1;
    }

    u16* Ew = (u16*)(pool + w * 8704);     // [32 q][136 d]
    float rl = (mode == 0) ? (1.f / Lrow) : 1.f;
#pragma unroll
    for (int nbd = 0; nbd < 4; nbd++)
#pragma unroll
      for (int r = 0; r < 16; r += 2){
        int d = nbd * 32 + (r & 3) + 8 * (r >> 2) + hi4;
        u32 wpk = pkr(Ov[nbd][r] * rl, Ov[nbd][r + 1] * rl);
        *(u32*)((char*)Ew + q5 * 272 + d * 2) = wpk;
      }
    if (mode == 0){
#pragma unroll
      for (int pass = 0; pass < 8; pass++){
        int q2 = pass * 4 + (l >> 4);
        short8 ov = *(const short8*)((char*)Ew + q2 * 272 + (l & 15) * 16);
        *(short8*)(Aout + (size_t)(qbase + q2) * QDIM + h * HD + (l & 15) * 8) = ov;
      }
    } else {
      const int p = mode - 1;
      u16* dstb = PO + ((size_t)((p * 16 + pr) * NH + h) * 128) * 128;
#pragma unroll
      for (int pass = 0; pass < 8; pass++){
        int q2 = pass * 4 + (l >> 4);
        short8 ov = *(const short8*)((char*)Ew + q2 * 272 + (l & 15) * 16);
        *(short8*)(dstb + (size_t)(w * 32 + q2) * 128 + (l & 15) * 8) = ov;
      }
      if (hi == 0){
        int idx = ((p * 16 + pr) * NH + h) * 128 + w * 32 + q5;
        mP[idx] = ms;
        LP[idx] = Lrow;
      }
    }
  }
}

// ---------------- combine partials for qt_hi = 31 - pr ----------------
__global__ __launch_bounds__(256) void combine_kernel(const u16* __restrict__ PO, const float* __restrict__ mP,
                                                      const float* __restrict__ LP, u16* __restrict__ Aout){
  const int pr = blockIdx.x;
  const int h  = blockIdx.y;
  const int tid = threadIdx.x;
  const int r  = tid >> 1;             // 0..127
  const int dh = (tid & 1) * 64;
  const int qhi = 31 - pr;
  const int idx0 = ((0 * 16 + pr) * NH + h) * 128 + r;
  const int idx1 = ((1 * 16 + pr) * NH + h) * 128 + r;
  float m0 = mP[idx0], m1 = mP[idx1];
  float L0 = LP[idx0], L1 = LP[idx1];
  float M = fmaxf(m0, m1);
  float a0 = __builtin_amdgcn_exp2f(m0 - M);
  float a1 = __builtin_amdgcn_exp2f(m1 - M);
  float rl = 1.f / (L0 * a0 + L1 * a1);
  const u16* o0 = PO + (size_t)idx0 * 128 + dh;
  const u16* o1 = PO + (size_t)idx1 * 128 + dh;
  u16* dst = Aout + (size_t)(qhi * 128 + r) * QDIM + h * HD + dh;
#pragma unroll
  for (int ch = 0; ch < 8; ch++){
    short8 v0 = *(const short8*)(o0 + ch * 8);
    short8 v1 = *(const short8*)(o1 + ch * 8);
    u32x4 ow;
#pragma unroll
    for (int j = 0; j < 4; j++){
      float e0 = (bf2f((u16)v0[2*j])   * a0 + bf2f((u16)v1[2*j])   * a1) * rl;
      float e1 = (bf2f((u16)v0[2*j+1]) * a0 + bf2f((u16)v1[2*j+1]) * a1) * rl;
      ow[j] = pkr(e0, e1);
    }
    *(u32x4*)(dst + ch * 8) = ow;
  }
}

extern "C" void kernel_launch(void* const* d_in, const int* in_sizes, int n_in,
                              void* d_out, int out_size, void* d_ws, size_t ws_size,
                              hipStream_t stream){
  const float* x  = (const float*)d_in[0];
  const float* Wq = (const float*)d_in[1];
  const float* Wk = (const float*)d_in[2];
  const float* Wv = (const float*)d_in[3];
  const float* Wo = (const float*)d_in[4];

  char* p = (char*)d_ws;
  u16* xb    = (u16*)p; p += (size_t)SEQN * HID * 2;
  u16* Wqkvb = (u16*)p; p += (size_t)QKVS * HID * 2;
  u16* Wob   = (u16*)p; p += (size_t)HID * QDIM * 2;
  u16* QKVb  = (u16*)p; p += (size_t)SEQN * QKVS * 2;
  u16* Ab    = (u16*)p; p += (size_t)SEQN * QDIM * 2;
  u16* VTg   = (u16*)p; p += (size_t)SEQN * KVD * 2;
  u16* PO    = (u16*)p; p += (size_t)2 * 16 * NH * 128 * 128 * 2;   // 16 MB
  float* mP  = (float*)p; p += (size_t)2 * 16 * NH * 128 * 4;
  float* LP  = (float*)p; p += (size_t)2 * 16 * NH * 128 * 4;

  const int totg = G1 + G2 + G3 + G4 + G5;
  cvt5_kernel<<<(totg + 255) / 256, 256, 0, stream>>>(x, Wq, Wk, Wv, Wo, xb, Wqkvb, Wob);

  gemm_kernel<0><<<dim3(SEQN/128, QKVS/128), 256, 0, stream>>>(xb, Wqkvb, QKVb, SEQN, QKVS, HID, QKVS);

  prep_kernel<<<ROPE_BLKS + (SEQN/64) * (KVD/64), 256, 0, stream>>>(QKVb, VTg);

  attn_kernel<<<dim3(16, NH, 2), 256, 0, stream>>>(QKVb, QKVb + QDIM, VTg, Ab, PO, mP, LP);
  combine_kernel<<<dim3(16, NH), 256, 0, stream>>>(PO, mP, LP, Ab);

  gemm_kernel<1><<<dim3(SEQN/128, HID/128), 256, 0, stream>>>(Ab, Wob, d_out, SEQN, HID, QDIM, HID);
}

// Round 15
// 253.081 us; speedup vs baseline: 1.0617x; 1.0617x over previous
//
#include <hip/hip_runtime.h>
#include <hip/hip_bf16.h>

typedef unsigned short u16;
typedef unsigned int u32;
typedef short short8 __attribute__((ext_vector_type(8)));
typedef unsigned short ushort4v __attribute__((ext_vector_type(4)));
typedef float f32x4 __attribute__((ext_vector_type(4)));
typedef float f32x16 __attribute__((ext_vector_type(16)));
typedef u32 u32x4 __attribute__((ext_vector_type(4)));

#define SEQN 4096
#define HID 2048
#define NH 16
#define NKV 4
#define HD 128
#define QDIM 2048   // NH*HD
#define KVD 512     // NKV*HD
#define QKVS 3072   // fused QKV row stride

static __device__ __forceinline__ float bf2f(u16 u){
  unsigned x = ((unsigned)u) << 16; float f; __builtin_memcpy(&f, &x, 4); return f;
}
static __device__ __forceinline__ u16 f2bf(float f){
  unsigned x; __builtin_memcpy(&x, &f, 4);
  x += 0x7fffu + ((x >> 16) & 1u);
  return (u16)(x >> 16);
}
// cheap round-half-up bf16 (<=1 ulp vs RNE)
static __device__ __forceinline__ u16 f2bfc(float f){
  unsigned x; __builtin_memcpy(&x, &f, 4);
  return (u16)((x + 0x8000u) >> 16);
}
// cheap packed pair: low16 = bf16(a), high16 = bf16(b)
static __device__ __forceinline__ u32 pkr(float a, float b){
  u32 ab, bb; __builtin_memcpy(&ab, &a, 4); __builtin_memcpy(&bb, &b, 4);
  return ((ab + 0x8000u) >> 16) | ((bb + 0x8000u) & 0xffff0000u);
}

// ---------------- fused fp32 -> bf16 convert (all 5 inputs, one launch) ----------------
#define G1 (SEQN*HID/4)
#define G2 (QDIM*HID/4)
#define G3 (KVD*HID/4)
#define G4 (KVD*HID/4)
#define G5 (HID*QDIM/4)
__global__ __launch_bounds__(256) void cvt5_kernel(const float* __restrict__ x,  const float* __restrict__ Wq,
                                                   const float* __restrict__ Wk, const float* __restrict__ Wv,
                                                   const float* __restrict__ Wo, u16* __restrict__ xb,
                                                   u16* __restrict__ Wqkvb, u16* __restrict__ Wob){
  int g = blockIdx.x * 256 + threadIdx.x;
  const float* src; u16* dst; int off;
  if (g < G1)                { src = x;  dst = xb;    off = g; }
  else if (g < G1+G2)        { src = Wq; dst = Wqkvb; off = g - G1; }
  else if (g < G1+G2+G3)     { src = Wk; dst = Wqkvb + (size_t)QDIM*HID;        off = g - (G1+G2); }
  else if (g < G1+G2+G3+G4)  { src = Wv; dst = Wqkvb + (size_t)(QDIM+KVD)*HID;  off = g - (G1+G2+G3); }
  else if (g < G1+G2+G3+G4+G5){ src = Wo; dst = Wob;  off = g - (G1+G2+G3+G4); }
  else return;
  f32x4 v = ((const f32x4*)src)[off];
  ushort4v o;
  o.x = f2bf(v.x); o.y = f2bf(v.y); o.z = f2bf(v.z); o.w = f2bf(v.w);
  ((ushort4v*)dst)[off] = o;
}

// ---------------- fused RoPE (Q,K) + V transpose, one launch ----------------
#define ROPE_BLKS (SEQN * (NH + NKV) * 16 / 256)     // 5120
__global__ __launch_bounds__(256) void prep_kernel(u16* __restrict__ QKVb, u16* __restrict__ VTg){
  __shared__ u16 T[64][72];
  const int bid = blockIdx.x;
  const int tid = threadIdx.x;
  if (bid < ROPE_BLKS){
    int idx = bid * 256 + tid;                 // one thread = 8 elems (4 pairs)
    int i8 = idx & 15;
    int rest = idx >> 4;
    int h = rest % (NH + NKV);
    int s = rest / (NH + NKV);
    int col = (h < NH) ? h * HD : QDIM + (h - NH) * HD;
    u16* p = QKVb + (size_t)s * QKVS + col + i8 * 8;
    short8 v = *(const short8*)p;
    short8 o;
#pragma unroll
    for (int j = 0; j < 4; j++){
      int i = i8 * 4 + j;
      float freq = expf(-0.14391156831212788f * (float)i);
      float ang = (float)s * freq;
      float c = cosf(ang), sn = sinf(ang);
      float x1 = bf2f((u16)v[2*j]), x2 = bf2f((u16)v[2*j+1]);
      o[2*j]   = (short)f2bfc(x1 * c - x2 * sn);
      o[2*j+1] = (short)f2bfc(x1 * sn + x2 * c);
    }
    *(short8*)p = o;
  } else {
    const int b2 = bid - ROPE_BLKS;
    const int s0 = (b2 & 63) * 64;
    const int c0 = (b2 >> 6) * 64;
    const int sl = tid & 63, ch = tid >> 6;
    const u16* src = QKVb + QDIM + KVD + (size_t)(s0 + sl) * QKVS + c0 + ch * 16;
    *(short8*)&T[sl][ch * 16]     = *(const short8*)(src);
    *(short8*)&T[sl][ch * 16 + 8] = *(const short8*)(src + 8);
    __syncthreads();
#pragma unroll
    for (int it = 0; it < 16; it++){
      int c = it * 4 + ch;
      VTg[(size_t)(c0 + c) * SEQN + s0 + sl] = T[sl][c];
    }
  }
}

// ---------------- async global->LDS 16B ----------------
static __device__ __forceinline__ void gload16(const void* g, void* l){
  __builtin_amdgcn_global_load_lds((const __attribute__((address_space(1))) void*)g,
                                   (__attribute__((address_space(3))) void*)l, 16, 0, 0);
}

// ---------------- GEMM: C[M][N(ldc)] = A[M][K] * B[N][K]^T ----------------
// BK=64, T2 chunk-XOR swizzle: pre-swizzled global_load_lds source (linear LDS dest),
// XOR'd ds_read index -> conflict-free b128 reads. bf16 out via LDS-transpose epilogue.
template<int F32OUT>
__global__ __launch_bounds__(256) void gemm_kernel(const u16* __restrict__ A, const u16* __restrict__ B,
                                                   void* __restrict__ Cout, int M, int N, int Kd, int ldc){
  __shared__ alignas(16) u16 sh[16384];         // As = sh[0..8192), Bs = sh[8192..16384)
  u16* As = sh;
  u16* Bs = sh + 8192;
  const int tid = threadIdx.x;
  const int w = tid >> 6, l = tid & 63;
  const int wr = w >> 1, wc = w & 1;
  const int lc = l & 15, lg = l >> 4;
  const int tm = blockIdx.x * 128, tn = blockIdx.y * 128;

  // staging: block b (of 16) = rows b*8..b*8+7 (8 rows x 128B). Lane l -> row b*8+(l>>3),
  // LDS chunk l&7 holds global k-chunk (l&7)^((l>>3)&7)  (row&7 == (l>>3)&7).
  const int srow8 = l >> 3;
  const int gch   = (l & 7) ^ (srow8 & 7);
  const u16* Asrc[4];
  const u16* Bsrc[4];
#pragma unroll
  for (int i = 0; i < 4; i++){
    int b = w * 4 + i;
    int row = b * 8 + srow8;
    Asrc[i] = A + (size_t)(tm + row) * Kd + gch * 8;
    Bsrc[i] = B + (size_t)(tn + row) * Kd + gch * 8;
  }

  f32x4 acc[4][4] = {};

  const int rsw = lc & 7;                       // row&7 for fragment reads

  for (int k0 = 0; k0 < Kd; k0 += 64){
#pragma unroll
    for (int i = 0; i < 4; i++)
      gload16(Asrc[i] + k0, As + (w * 4 + i) * 512);
#pragma unroll
    for (int i = 0; i < 4; i++)
      gload16(Bsrc[i] + k0, Bs + (w * 4 + i) * 512);
    __syncthreads();
    short8 a[4][2], b[4][2];
#pragma unroll
    for (int mi = 0; mi < 4; mi++)
#pragma unroll
      for (int kk = 0; kk < 2; kk++)
        a[mi][kk] = *(const short8*)&As[(wr*64 + mi*16 + lc) * 64 + (((kk*4 + lg) ^ rsw) * 8)];
#pragma unroll
    for (int ni = 0; ni < 4; ni++)
#pragma unroll
      for (int kk = 0; kk < 2; kk++)
        b[ni][kk] = *(const short8*)&Bs[(wc*64 + ni*16 + lc) * 64 + (((kk*4 + lg) ^ rsw) * 8)];
#pragma unroll
    for (int kk = 0; kk < 2; kk++)
#pragma unroll
      for (int mi = 0; mi < 4; mi++)
#pragma unroll
        for (int ni = 0; ni < 4; ni++)
          acc[mi][ni] = __builtin_amdgcn_mfma_f32_16x16x32_bf16(a[mi][kk], b[ni][kk], acc[mi][ni], 0, 0, 0);
    __syncthreads();
  }

  if (F32OUT){
#pragma unroll
    for (int mi = 0; mi < 4; mi++)
#pragma unroll
      for (int ni = 0; ni < 4; ni++)
#pragma unroll
        for (int r = 0; r < 4; r++){
          int row = tm + wr*64 + mi*16 + lg*4 + r;
          int col = tn + wc*64 + ni*16 + lc;
          ((float*)Cout)[(size_t)row * ldc + col] = acc[mi][ni][r];
        }
  } else {
    __syncthreads();
    u16* Ew = sh + w * 1168;               // [16][73] u16 per wave
#pragma unroll
    for (int mi = 0; mi < 4; mi++){
#pragma unroll
      for (int ni = 0; ni < 4; ni++)
#pragma unroll
        for (int r = 0; r < 4; r++)
          Ew[(lg * 4 + r) * 73 + ni * 16 + lc] = f2bfc(acc[mi][ni][r]);
#pragma unroll
      for (int pass = 0; pass < 2; pass++){
        int row = pass * 8 + (l >> 3);
        short8 v;
#pragma unroll
        for (int j = 0; j < 8; j++) v[j] = (short)Ew[row * 73 + (l & 7) * 8 + j];
        *(short8*)((u16*)Cout + (size_t)(tm + wr*64 + mi*16 + row) * ldc + tn + wc*64 + (l & 7) * 8) = v;
      }
    }
  }
}

// ---------------- Flash attention (causal, GQA), KV-split uniform blocks (r13) ----------------
__global__ __launch_bounds__(256, 2) void attn_kernel(const u16* __restrict__ Qg, const u16* __restrict__ Kgb,
                                                      const u16* __restrict__ VTg, u16* __restrict__ Aout,
                                                      u16* __restrict__ PO, float* __restrict__ mP,
                                                      float* __restrict__ LP){
  __shared__ alignas(16) char pool[65536];   // 2 x (Ks 16KB + VT 16KB)

  const int pr  = blockIdx.x;            // 0..15
  const int h   = blockIdx.y;
  const int s   = blockIdx.z;
  const int kvh = h >> 2;
  const int tid = threadIdx.x;
  const int w = tid >> 6, l = tid & 63;
  const int q5 = l & 31;
  const int hi = l >> 5;
  const int hi4 = hi * 4;
  const float csc = 0.12751743f;         // (1/sqrt(128)) * log2(e)

  const u16* Ksrc[4];
  const u16* Vsrc[4];
#pragma unroll
  for (int i = 0; i < 4; i++){
    int blk = w * 4 + i;
    int row = blk * 4 + (l >> 4);
    int cg  = (l & 15) ^ (row & 15);
    Ksrc[i] = Kgb + (size_t)row * QKVS + kvh * HD + cg * 8;
    int d   = blk * 8 + (l >> 3);
    int cv  = (l & 7) ^ (d & 7);
    Vsrc[i] = VTg + (size_t)(kvh * 128 + d) * SEQN + cv * 8;
  }

  auto issueTile = [&](int b, int kv0){
    char* Ksb = pool + b * 32768;
    char* VTb = Ksb + 16384;
#pragma unroll
    for (int i = 0; i < 4; i++)
      gload16(Ksrc[i] + (size_t)kv0 * QKVS, Ksb + (w * 4 + i) * 1024);
#pragma unroll
    for (int i = 0; i < 4; i++)
      gload16(Vsrc[i] + kv0, VTb + (w * 4 + i) * 1024);
  };

  const int qlo = pr, qhi = 31 - pr;
  int nseg, sq[2], st0[2], st1[2], smode[2];   // mode: 0 final, 1 partial0, 2 partial1
  if (s == 0){
    nseg = 2;
    sq[0] = qlo; st0[0] = 0;           st1[0] = 2 * pr + 2;   smode[0] = 0;
    sq[1] = qhi; st0[1] = 0;           st1[1] = 31 - 2 * pr;  smode[1] = 1;
  } else {
    nseg = 1;
    sq[0] = qhi; st0[0] = 31 - 2 * pr; st1[0] = 64 - 2 * pr;  smode[0] = 2;
  }

  for (int sg = 0; sg < nseg; sg++){
    const int qt = sq[sg], t0 = st0[sg], t1 = st1[sg], mode = smode[sg];
    const int qbase = qt * 128 + w * 32;
    const int qa    = qbase + q5;

    short8 qf[8];
    {
      const u16* qp = Qg + (size_t)(qbase + q5) * QKVS + h * HD + hi * 8;
#pragma unroll
      for (int k0 = 0; k0 < 8; k0++) qf[k0] = *(const short8*)(qp + k0 * 16);
    }

    f32x16 Ov[4] = {};
    float Lrow = 0.f;
    float ms = -1e30f;

    auto computeTile = [&](int b, int kv0){
      if (kv0 > qbase + 31) return;
      char* Ksb = pool + b * 32768;
      char* VTb = Ksb + 16384;
      f32x16 Sv[2] = {};
#pragma unroll
      for (int k0 = 0; k0 < 8; k0++){
#pragma unroll
        for (int nb = 0; nb < 2; nb++){
          int kvr = nb * 32 + q5;
          short8 kf = *(const short8*)(Ksb + kvr * 256 + (((k0 * 2 + hi) ^ (kvr & 15)) << 4));
          Sv[nb] = __builtin_amdgcn_mfma_f32_32x32x16_bf16(kf, qf[k0], Sv[nb], 0, 0, 0);
        }
      }
      if (kv0 + 63 > qbase){
#pragma unroll
        for (int nb = 0; nb < 2; nb++)
#pragma unroll
          for (int r = 0; r < 16; r++){
            int kva = kv0 + nb * 32 + (r & 3) + 8 * (r >> 2) + hi4;
            if (kva > qa) Sv[nb][r] = -1e30f;
          }
      }
      float tm = fmaxf(Sv[0][0], Sv[0][1]);
#pragma unroll
      for (int nb = 0; nb < 2; nb++)
#pragma unroll
        for (int r = (nb == 0 ? 2 : 0); r < 16; r += 2)
          tm = fmaxf(tm, fmaxf(Sv[nb][r], Sv[nb][r + 1]));
      tm = fmaxf(tm, __shfl_xor(tm, 32));
      float tms = tm * csc;
      if (!__all(tms - ms <= 8.f)){
        float nms = fmaxf(ms, tms);
        float al = __builtin_amdgcn_exp2f(ms - nms);
        ms = nms;
        Lrow *= al;
#pragma unroll
        for (int nb = 0; nb < 4; nb++)
#pragma unroll
          for (int r = 0; r < 16; r++) Ov[nb][r] *= al;
      }
      float ts0 = 0.f, ts1 = 0.f;
#pragma unroll
      for (int nb = 0; nb < 2; nb++)
#pragma unroll
        for (int r = 0; r < 16; r += 2){
          float p0 = __builtin_amdgcn_exp2f(__builtin_fmaf(Sv[nb][r],     csc, -ms));
          float p1 = __builtin_amdgcn_exp2f(__builtin_fmaf(Sv[nb][r + 1], csc, -ms));
          Sv[nb][r] = p0; Sv[nb][r + 1] = p1;
          ts0 += p0; ts1 += p1;
        }
      float ts = ts0 + ts1;
      ts += __shfl_xor(ts, 32);
      Lrow += ts;
#pragma unroll
      for (int kc = 0; kc < 4; kc++){
        const int nb = kc >> 1, rb = (kc & 1) * 8;
        u32 Aw = pkr(Sv[nb][rb + 0], Sv[nb][rb + 1]);
        u32 Bw = pkr(Sv[nb][rb + 2], Sv[nb][rb + 3]);
        u32 Cw = pkr(Sv[nb][rb + 4], Sv[nb][rb + 5]);
        u32 Dw = pkr(Sv[nb][rb + 6], Sv[nb][rb + 7]);
        u32 sAw = __shfl_xor(Aw, 32);
        u32 sBw = __shfl_xor(Bw, 32);
        u32 sCw = __shfl_xor(Cw, 32);
        u32 sDw = __shfl_xor(Dw, 32);
        u32 w0 = hi ? sCw : Aw;
        u32 w1 = hi ? sDw : Bw;
        u32 w2 = hi ? Cw : sAw;
        u32 w3 = hi ? Dw : sBw;
        u32x4 pw4 = {w0, w1, w2, w3};
        short8 pf = *(short8*)&pw4;
#pragma unroll
        for (int nbd = 0; nbd < 4; nbd++){
          int drow = nbd * 32 + q5;
          short8 vf = *(const short8*)(VTb + drow * 128 + (((kc * 2 + hi) ^ (drow & 7)) << 4));
          Ov[nbd] = __builtin_amdgcn_mfma_f32_32x32x16_bf16(vf, pf, Ov[nbd], 0, 0, 0);
        }
      }
    };

    __syncthreads();                 // prior segment's pool reads done
    issueTile(0, t0 * 64);
    __syncthreads();                 // buf0 landed
    int cur = 0;
    for (int t = t0; t < t1; t++){
      if (t + 1 < t1) issueTile(cur ^ 1, (t + 1) * 64);
      computeTile(cur, t * 64);
      __syncthreads();
      cur ^= 1;
    }

    u16* Ew = (u16*)(pool + w * 8704);     // [32 q][136 d]
    float rl = (mode == 0) ? (1.f / Lrow) : 1.f;
#pragma unroll
    for (int nbd = 0; nbd < 4; nbd++)
#pragma unroll
      for (int r = 0; r < 16; r += 2){
        int d = nbd * 32 + (r & 3) + 8 * (r >> 2) + hi4;
        u32 wpk = pkr(Ov[nbd][r] * rl, Ov[nbd][r + 1] * rl);
        *(u32*)((char*)Ew + q5 * 272 + d * 2) = wpk;
      }
    if (mode == 0){
#pragma unroll
      for (int pass = 0; pass < 8; pass++){
        int q2 = pass * 4 + (l >> 4);
        short8 ov = *(const short8*)((char*)Ew + q2 * 272 + (l & 15) * 16);
        *(short8*)(Aout + (size_t)(qbase + q2) * QDIM + h * HD + (l & 15) * 8) = ov;
      }
    } else {
      const int p = mode - 1;
      u16* dstb = PO + ((size_t)((p * 16 + pr) * NH + h) * 128) * 128;
#pragma unroll
      for (int pass = 0; pass < 8; pass++){
        int q2 = pass * 4 + (l >> 4);
        short8 ov = *(const short8*)((char*)Ew + q2 * 272 + (l & 15) * 16);
        *(short8*)(dstb + (size_t)(w * 32 + q2) * 128 + (l & 15) * 8) = ov;
      }
      if (hi == 0){
        int idx = ((p * 16 + pr) * NH + h) * 128 + w * 32 + q5;
        mP[idx] = ms;
        LP[idx] = Lrow;
      }
    }
  }
}

// ---------------- combine partials for qt_hi = 31 - pr ----------------
__global__ __launch_bounds__(256) void combine_kernel(const u16* __restrict__ PO, const float* __restrict__ mP,
                                                      const float* __restrict__ LP, u16* __restrict__ Aout){
  const int pr = blockIdx.x;
  const int h  = blockIdx.y;
  const int tid = threadIdx.x;
  const int r  = tid >> 1;             // 0..127
  const int dh = (tid & 1) * 64;
  const int qhi = 31 - pr;
  const int idx0 = ((0 * 16 + pr) * NH + h) * 128 + r;
  const int idx1 = ((1 * 16 + pr) * NH + h) * 128 + r;
  float m0 = mP[idx0], m1 = mP[idx1];
  float L0 = LP[idx0], L1 = LP[idx1];
  float M = fmaxf(m0, m1);
  float a0 = __builtin_amdgcn_exp2f(m0 - M);
  float a1 = __builtin_amdgcn_exp2f(m1 - M);
  float rl = 1.f / (L0 * a0 + L1 * a1);
  const u16* o0 = PO + (size_t)idx0 * 128 + dh;
  const u16* o1 = PO + (size_t)idx1 * 128 + dh;
  u16* dst = Aout + (size_t)(qhi * 128 + r) * QDIM + h * HD + dh;
#pragma unroll
  for (int ch = 0; ch < 8; ch++){
    short8 v0 = *(const short8*)(o0 + ch * 8);
    short8 v1 = *(const short8*)(o1 + ch * 8);
    u32x4 ow;
#pragma unroll
    for (int j = 0; j < 4; j++){
      float e0 = (bf2f((u16)v0[2*j])   * a0 + bf2f((u16)v1[2*j])   * a1) * rl;
      float e1 = (bf2f((u16)v0[2*j+1]) * a0 + bf2f((u16)v1[2*j+1]) * a1) * rl;
      ow[j] = pkr(e0, e1);
    }
    *(u32x4*)(dst + ch * 8) = ow;
  }
}

extern "C" void kernel_launch(void* const* d_in, const int* in_sizes, int n_in,
                              void* d_out, int out_size, void* d_ws, size_t ws_size,
                              hipStream_t stream){
  const float* x  = (const float*)d_in[0];
  const float* Wq = (const float*)d_in[1];
  const float* Wk = (const float*)d_in[2];
  const float* Wv = (const float*)d_in[3];
  const float* Wo = (const float*)d_in[4];

  char* p = (char*)d_ws;
  u16* xb    = (u16*)p; p += (size_t)SEQN * HID * 2;
  u16* Wqkvb = (u16*)p; p += (size_t)QKVS * HID * 2;
  u16* Wob   = (u16*)p; p += (size_t)HID * QDIM * 2;
  u16* QKVb  = (u16*)p; p += (size_t)SEQN * QKVS * 2;
  u16* Ab    = (u16*)p; p += (size_t)SEQN * QDIM * 2;
  u16* VTg   = (u16*)p; p += (size_t)SEQN * KVD * 2;
  u16* PO    = (u16*)p; p += (size_t)2 * 16 * NH * 128 * 128 * 2;   // 16 MB
  float* mP  = (float*)p; p += (size_t)2 * 16 * NH * 128 * 4;
  float* LP  = (float*)p; p += (size_t)2 * 16 * NH * 128 * 4;

  const int totg = G1 + G2 + G3 + G4 + G5;
  cvt5_kernel<<<(totg + 255) / 256, 256, 0, stream>>>(x, Wq, Wk, Wv, Wo, xb, Wqkvb, Wob);

  gemm_kernel<0><<<dim3(SEQN/128, QKVS/128), 256, 0, stream>>>(xb, Wqkvb, QKVb, SEQN, QKVS, HID, QKVS);

  prep_kernel<<<ROPE_BLKS + (SEQN/64) * (KVD/64), 256, 0, stream>>>(QKVb, VTg);

  attn_kernel<<<dim3(16, NH, 2), 256, 0, stream>>>(QKVb, QKVb + QDIM, VTg, Ab, PO, mP, LP);
  combine_kernel<<<dim3(16, NH), 256, 0, stream>>>(PO, mP, LP, Ab);

  gemm_kernel<1><<<dim3(SEQN/128, HID/128), 256, 0, stream>>>(Ab, Wob, d_out, SEQN, HID, QDIM, HID);
}

// Round 16
// 237.193 us; speedup vs baseline: 1.1328x; 1.0670x over previous
//
#include <hip/hip_runtime.h>
#include <hip/hip_bf16.h>

typedef unsigned short u16;
typedef unsigned int u32;
typedef short short8 __attribute__((ext_vector_type(8)));
typedef unsigned short ushort4v __attribute__((ext_vector_type(4)));
typedef float f32x4 __attribute__((ext_vector_type(4)));
typedef float f32x16 __attribute__((ext_vector_type(16)));
typedef u32 u32x4 __attribute__((ext_vector_type(4)));

#define SEQN 4096
#define HID 2048
#define NH 16
#define NKV 4
#define HD 128
#define QDIM 2048   // NH*HD
#define KVD 512     // NKV*HD
#define QKVS 3072   // fused QKV row stride

static __device__ __forceinline__ float bf2f(u16 u){
  unsigned x = ((unsigned)u) << 16; float f; __builtin_memcpy(&f, &x, 4); return f;
}
static __device__ __forceinline__ u16 f2bf(float f){
  unsigned x; __builtin_memcpy(&x, &f, 4);
  x += 0x7fffu + ((x >> 16) & 1u);
  return (u16)(x >> 16);
}
// cheap round-half-up bf16 (<=1 ulp vs RNE)
static __device__ __forceinline__ u16 f2bfc(float f){
  unsigned x; __builtin_memcpy(&x, &f, 4);
  return (u16)((x + 0x8000u) >> 16);
}
// cheap packed pair: low16 = bf16(a), high16 = bf16(b)
static __device__ __forceinline__ u32 pkr(float a, float b){
  u32 ab, bb; __builtin_memcpy(&ab, &a, 4); __builtin_memcpy(&bb, &b, 4);
  return ((ab + 0x8000u) >> 16) | ((bb + 0x8000u) & 0xffff0000u);
}

// ---------------- fused fp32 -> bf16 convert (all 5 inputs, one launch) ----------------
#define G1 (SEQN*HID/4)
#define G2 (QDIM*HID/4)
#define G3 (KVD*HID/4)
#define G4 (KVD*HID/4)
#define G5 (HID*QDIM/4)
__global__ __launch_bounds__(256) void cvt5_kernel(const float* __restrict__ x,  const float* __restrict__ Wq,
                                                   const float* __restrict__ Wk, const float* __restrict__ Wv,
                                                   const float* __restrict__ Wo, u16* __restrict__ xb,
                                                   u16* __restrict__ Wqkvb, u16* __restrict__ Wob){
  int g = blockIdx.x * 256 + threadIdx.x;
  const float* src; u16* dst; int off;
  if (g < G1)                { src = x;  dst = xb;    off = g; }
  else if (g < G1+G2)        { src = Wq; dst = Wqkvb; off = g - G1; }
  else if (g < G1+G2+G3)     { src = Wk; dst = Wqkvb + (size_t)QDIM*HID;        off = g - (G1+G2); }
  else if (g < G1+G2+G3+G4)  { src = Wv; dst = Wqkvb + (size_t)(QDIM+KVD)*HID;  off = g - (G1+G2+G3); }
  else if (g < G1+G2+G3+G4+G5){ src = Wo; dst = Wob;  off = g - (G1+G2+G3+G4); }
  else return;
  f32x4 v = ((const f32x4*)src)[off];
  ushort4v o;
  o.x = f2bf(v.x); o.y = f2bf(v.y); o.z = f2bf(v.z); o.w = f2bf(v.w);
  ((ushort4v*)dst)[off] = o;
}

// ---------------- fused RoPE (Q,K) + V transpose, one launch ----------------
#define ROPE_BLKS (SEQN * (NH + NKV) * 16 / 256)     // 5120
__global__ __launch_bounds__(256) void prep_kernel(u16* __restrict__ QKVb, u16* __restrict__ VTg){
  __shared__ u16 T[64][72];
  const int bid = blockIdx.x;
  const int tid = threadIdx.x;
  if (bid < ROPE_BLKS){
    int idx = bid * 256 + tid;                 // one thread = 8 elems (4 pairs)
    int i8 = idx & 15;
    int rest = idx >> 4;
    int h = rest % (NH + NKV);
    int s = rest / (NH + NKV);
    int col = (h < NH) ? h * HD : QDIM + (h - NH) * HD;
    u16* p = QKVb + (size_t)s * QKVS + col + i8 * 8;
    short8 v = *(const short8*)p;
    short8 o;
#pragma unroll
    for (int j = 0; j < 4; j++){
      int i = i8 * 4 + j;
      float freq = expf(-0.14391156831212788f * (float)i);
      float ang = (float)s * freq;
      float c = cosf(ang), sn = sinf(ang);
      float x1 = bf2f((u16)v[2*j]), x2 = bf2f((u16)v[2*j+1]);
      o[2*j]   = (short)f2bfc(x1 * c - x2 * sn);
      o[2*j+1] = (short)f2bfc(x1 * sn + x2 * c);
    }
    *(short8*)p = o;
  } else {
    const int b2 = bid - ROPE_BLKS;
    const int s0 = (b2 & 63) * 64;
    const int c0 = (b2 >> 6) * 64;
    const int sl = tid & 63, ch = tid >> 6;
    const u16* src = QKVb + QDIM + KVD + (size_t)(s0 + sl) * QKVS + c0 + ch * 16;
    *(short8*)&T[sl][ch * 16]     = *(const short8*)(src);
    *(short8*)&T[sl][ch * 16 + 8] = *(const short8*)(src + 8);
    __syncthreads();
#pragma unroll
    for (int it = 0; it < 16; it++){
      int c = it * 4 + ch;
      VTg[(size_t)(c0 + c) * SEQN + s0 + sl] = T[sl][c];
    }
  }
}

// ---------------- async global->LDS 16B ----------------
static __device__ __forceinline__ void gload16(const void* g, void* l){
  __builtin_amdgcn_global_load_lds((const __attribute__((address_space(1))) void*)g,
                                   (__attribute__((address_space(3))) void*)l, 16, 0, 0);
}

// ---------------- GEMM: C[M][N(ldc)] = A[M][K] * B[N][K]^T ----------------
// BK=32, 4-slot LDS ring (64KB), counted-vmcnt pipeline: stage(t+2) issued each iter,
// s_waitcnt vmcnt(8) (in-order count -> tile t landed) + raw s_barrier; loads stay in
// flight across barriers (T4). Chunk-XOR swizzle, pre-swizzled global_load_lds source.
template<int F32OUT>
__global__ __launch_bounds__(256) void gemm_kernel(const u16* __restrict__ A, const u16* __restrict__ B,
                                                   void* __restrict__ Cout, int M, int N, int Kd, int ldc){
  __shared__ alignas(16) u16 sh[32768];         // 4 slots x (A 4096 u16 + B 4096 u16)
  const int tid = threadIdx.x;
  const int w = tid >> 6, l = tid & 63;
  const int wr = w >> 1, wc = w & 1;
  const int lc = l & 15, lg = l >> 4;
  const int tm = blockIdx.x * 128, tn = blockIdx.y * 128;

  // staging: 16 blocks of 1KB per tile (A: blk 0-7, B: blk 8-15); wave w -> blk w*4..w*4+3
  // lane l -> row (blk&7)*16 + (l>>2), LDS chunk l&3 holds global chunk (l&3)^(row&3)
  const u16* src[4];
#pragma unroll
  for (int i = 0; i < 4; i++){
    int blk = w * 4 + i;
    int row = (blk & 7) * 16 + (l >> 2);
    int cs  = (l & 3) ^ (row & 3);
    src[i] = (blk < 8) ? (A + (size_t)(tm + row) * Kd + cs * 8)
                       : (B + (size_t)(tn + row) * Kd + cs * 8);
  }

  auto issueStage = [&](int slot, int t){
    char* base = (char*)sh + slot * 16384;
    int k0 = t * 32;
#pragma unroll
    for (int i = 0; i < 4; i++)
      gload16(src[i] + k0, base + (w * 4 + i) * 1024);
  };

  f32x4 acc[4][4] = {};
  const int T = Kd / 32;

  // prologue: tiles 0,1 into slots 0,1
  issueStage(0, 0);
  issueStage(1, 1);

  for (int t = 0; t < T; t++){
    if (t + 2 < T) issueStage((t + 2) & 3, t + 2);
    // wait for tile t's 4 loads (in-order vmcnt): outstanding allowed = stages after t
    if (t + 2 < T)      asm volatile("s_waitcnt vmcnt(8)" ::: "memory");
    else if (t + 1 < T) asm volatile("s_waitcnt vmcnt(4)" ::: "memory");
    else                asm volatile("s_waitcnt vmcnt(0)" ::: "memory");
    __builtin_amdgcn_s_barrier();
    __builtin_amdgcn_sched_barrier(0);

    const char* base = (const char*)sh + (t & 3) * 16384;
    short8 a[4], b[4];
#pragma unroll
    for (int mi = 0; mi < 4; mi++){
      int row = wr * 64 + mi * 16 + lc;
      a[mi] = *(const short8*)(base + row * 64 + ((lg ^ (row & 3)) * 16));
    }
#pragma unroll
    for (int ni = 0; ni < 4; ni++){
      int row = wc * 64 + ni * 16 + lc;
      b[ni] = *(const short8*)(base + 8192 + row * 64 + ((lg ^ (row & 3)) * 16));
    }
#pragma unroll
    for (int mi = 0; mi < 4; mi++)
#pragma unroll
      for (int ni = 0; ni < 4; ni++)
        acc[mi][ni] = __builtin_amdgcn_mfma_f32_16x16x32_bf16(a[mi], b[ni], acc[mi][ni], 0, 0, 0);
  }

  if (F32OUT){
#pragma unroll
    for (int mi = 0; mi < 4; mi++)
#pragma unroll
      for (int ni = 0; ni < 4; ni++)
#pragma unroll
        for (int r = 0; r < 4; r++){
          int row = tm + wr*64 + mi*16 + lg*4 + r;
          int col = tn + wc*64 + ni*16 + lc;
          ((float*)Cout)[(size_t)row * ldc + col] = acc[mi][ni][r];
        }
  } else {
    __syncthreads();                       // all waves done reading slots
    u16* Ew = sh + w * 1168;               // [16][73] u16 per wave
#pragma unroll
    for (int mi = 0; mi < 4; mi++){
#pragma unroll
      for (int ni = 0; ni < 4; ni++)
#pragma unroll
        for (int r = 0; r < 4; r++)
          Ew[(lg * 4 + r) * 73 + ni * 16 + lc] = f2bfc(acc[mi][ni][r]);
#pragma unroll
      for (int pass = 0; pass < 2; pass++){
        int row = pass * 8 + (l >> 3);
        short8 v;
#pragma unroll
        for (int j = 0; j < 8; j++) v[j] = (short)Ew[row * 73 + (l & 7) * 8 + j];
        *(short8*)((u16*)Cout + (size_t)(tm + wr*64 + mi*16 + row) * ldc + tn + wc*64 + (l & 7) * 8) = v;
      }
    }
  }
}

// ---------------- Flash attention (causal, GQA), KV-split uniform blocks (r13/r15) ----------------
__global__ __launch_bounds__(256, 2) void attn_kernel(const u16* __restrict__ Qg, const u16* __restrict__ Kgb,
                                                      const u16* __restrict__ VTg, u16* __restrict__ Aout,
                                                      u16* __restrict__ PO, float* __restrict__ mP,
                                                      float* __restrict__ LP){
  __shared__ alignas(16) char pool[65536];   // 2 x (Ks 16KB + VT 16KB)

  const int pr  = blockIdx.x;            // 0..15
  const int h   = blockIdx.y;
  const int s   = blockIdx.z;
  const int kvh = h >> 2;
  const int tid = threadIdx.x;
  const int w = tid >> 6, l = tid & 63;
  const int q5 = l & 31;
  const int hi = l >> 5;
  const int hi4 = hi * 4;
  const float csc = 0.12751743f;         // (1/sqrt(128)) * log2(e)

  const u16* Ksrc[4];
  const u16* Vsrc[4];
#pragma unroll
  for (int i = 0; i < 4; i++){
    int blk = w * 4 + i;
    int row = blk * 4 + (l >> 4);
    int cg  = (l & 15) ^ (row & 15);
    Ksrc[i] = Kgb + (size_t)row * QKVS + kvh * HD + cg * 8;
    int d   = blk * 8 + (l >> 3);
    int cv  = (l & 7) ^ (d & 7);
    Vsrc[i] = VTg + (size_t)(kvh * 128 + d) * SEQN + cv * 8;
  }

  auto issueTile = [&](int b, int kv0){
    char* Ksb = pool + b * 32768;
    char* VTb = Ksb + 16384;
#pragma unroll
    for (int i = 0; i < 4; i++)
      gload16(Ksrc[i] + (size_t)kv0 * QKVS, Ksb + (w * 4 + i) * 1024);
#pragma unroll
    for (int i = 0; i < 4; i++)
      gload16(Vsrc[i] + kv0, VTb + (w * 4 + i) * 1024);
  };

  const int qlo = pr, qhi = 31 - pr;
  int nseg, sq[2], st0[2], st1[2], smode[2];   // mode: 0 final, 1 partial0, 2 partial1
  if (s == 0){
    nseg = 2;
    sq[0] = qlo; st0[0] = 0;           st1[0] = 2 * pr + 2;   smode[0] = 0;
    sq[1] = qhi; st0[1] = 0;           st1[1] = 31 - 2 * pr;  smode[1] = 1;
  } else {
    nseg = 1;
    sq[0] = qhi; st0[0] = 31 - 2 * pr; st1[0] = 64 - 2 * pr;  smode[0] = 2;
  }

  for (int sg = 0; sg < nseg; sg++){
    const int qt = sq[sg], t0 = st0[sg], t1 = st1[sg], mode = smode[sg];
    const int qbase = qt * 128 + w * 32;
    const int qa    = qbase + q5;

    short8 qf[8];
    {
      const u16* qp = Qg + (size_t)(qbase + q5) * QKVS + h * HD + hi * 8;
#pragma unroll
      for (int k0 = 0; k0 < 8; k0++) qf[k0] = *(const short8*)(qp + k0 * 16);
    }

    f32x16 Ov[4] = {};
    float Lrow = 0.f;
    float ms = -1e30f;

    auto computeTile = [&](int b, int kv0){
      if (kv0 > qbase + 31) return;
      char* Ksb = pool + b * 32768;
      char* VTb = Ksb + 16384;
      f32x16 Sv[2] = {};
#pragma unroll
      for (int k0 = 0; k0 < 8; k0++){
#pragma unroll
        for (int nb = 0; nb < 2; nb++){
          int kvr = nb * 32 + q5;
          short8 kf = *(const short8*)(Ksb + kvr * 256 + (((k0 * 2 + hi) ^ (kvr & 15)) << 4));
          Sv[nb] = __builtin_amdgcn_mfma_f32_32x32x16_bf16(kf, qf[k0], Sv[nb], 0, 0, 0);
        }
      }
      if (kv0 + 63 > qbase){
#pragma unroll
        for (int nb = 0; nb < 2; nb++)
#pragma unroll
          for (int r = 0; r < 16; r++){
            int kva = kv0 + nb * 32 + (r & 3) + 8 * (r >> 2) + hi4;
            if (kva > qa) Sv[nb][r] = -1e30f;
          }
      }
      float tm = fmaxf(Sv[0][0], Sv[0][1]);
#pragma unroll
      for (int nb = 0; nb < 2; nb++)
#pragma unroll
        for (int r = (nb == 0 ? 2 : 0); r < 16; r += 2)
          tm = fmaxf(tm, fmaxf(Sv[nb][r], Sv[nb][r + 1]));
      tm = fmaxf(tm, __shfl_xor(tm, 32));
      float tms = tm * csc;
      if (!__all(tms - ms <= 8.f)){
        float nms = fmaxf(ms, tms);
        float al = __builtin_amdgcn_exp2f(ms - nms);
        ms = nms;
        Lrow *= al;
#pragma unroll
        for (int nb = 0; nb < 4; nb++)
#pragma unroll
          for (int r = 0; r < 16; r++) Ov[nb][r] *= al;
      }
      float ts0 = 0.f, ts1 = 0.f;
#pragma unroll
      for (int nb = 0; nb < 2; nb++)
#pragma unroll
        for (int r = 0; r < 16; r += 2){
          float p0 = __builtin_amdgcn_exp2f(__builtin_fmaf(Sv[nb][r],     csc, -ms));
          float p1 = __builtin_amdgcn_exp2f(__builtin_fmaf(Sv[nb][r + 1], csc, -ms));
          Sv[nb][r] = p0; Sv[nb][r + 1] = p1;
          ts0 += p0; ts1 += p1;
        }
      float ts = ts0 + ts1;
      ts += __shfl_xor(ts, 32);
      Lrow += ts;
#pragma unroll
      for (int kc = 0; kc < 4; kc++){
        const int nb = kc >> 1, rb = (kc & 1) * 8;
        u32 Aw = pkr(Sv[nb][rb + 0], Sv[nb][rb + 1]);
        u32 Bw = pkr(Sv[nb][rb + 2], Sv[nb][rb + 3]);
        u32 Cw = pkr(Sv[nb][rb + 4], Sv[nb][rb + 5]);
        u32 Dw = pkr(Sv[nb][rb + 6], Sv[nb][rb + 7]);
        u32 sAw = __shfl_xor(Aw, 32);
        u32 sBw = __shfl_xor(Bw, 32);
        u32 sCw = __shfl_xor(Cw, 32);
        u32 sDw = __shfl_xor(Dw, 32);
        u32 w0 = hi ? sCw : Aw;
        u32 w1 = hi ? sDw : Bw;
        u32 w2 = hi ? Cw : sAw;
        u32 w3 = hi ? Dw : sBw;
        u32x4 pw4 = {w0, w1, w2, w3};
        short8 pf = *(short8*)&pw4;
#pragma unroll
        for (int nbd = 0; nbd < 4; nbd++){
          int drow = nbd * 32 + q5;
          short8 vf = *(const short8*)(VTb + drow * 128 + (((kc * 2 + hi) ^ (drow & 7)) << 4));
          Ov[nbd] = __builtin_amdgcn_mfma_f32_32x32x16_bf16(vf, pf, Ov[nbd], 0, 0, 0);
        }
      }
    };

    __syncthreads();                 // prior segment's pool reads done
    issueTile(0, t0 * 64);
    __syncthreads();                 // buf0 landed
    int cur = 0;
    for (int t = t0; t < t1; t++){
      if (t + 1 < t1) issueTile(cur ^ 1, (t + 1) * 64);
      computeTile(cur, t * 64);
      __syncthreads();
      cur ^= 1;
    }

    u16* Ew = (u16*)(pool + w * 8704);     // [32 q][136 d]
    float rl = (mode == 0) ? (1.f / Lrow) : 1.f;
#pragma unroll
    for (int nbd = 0; nbd < 4; nbd++)
#pragma unroll
      for (int r = 0; r < 16; r += 2){
        int d = nbd * 32 + (r & 3) + 8 * (r >> 2) + hi4;
        u32 wpk = pkr(Ov[nbd][r] * rl, Ov[nbd][r + 1] * rl);
        *(u32*)((char*)Ew + q5 * 272 + d * 2) = wpk;
      }
    if (mode == 0){
#pragma unroll
      for (int pass = 0; pass < 8; pass++){
        int q2 = pass * 4 + (l >> 4);
        short8 ov = *(const short8*)((char*)Ew + q2 * 272 + (l & 15) * 16);
        *(short8*)(Aout + (size_t)(qbase + q2) * QDIM + h * HD + (l & 15) * 8) = ov;
      }
    } else {
      const int p = mode - 1;
      u16* dstb = PO + ((size_t)((p * 16 + pr) * NH + h) * 128) * 128;
#pragma unroll
      for (int pass = 0; pass < 8; pass++){
        int q2 = pass * 4 + (l >> 4);
        short8 ov = *(const short8*)((char*)Ew + q2 * 272 + (l & 15) * 16);
        *(short8*)(dstb + (size_t)(w * 32 + q2) * 128 + (l & 15) * 8) = ov;
      }
      if (hi == 0){
        int idx = ((p * 16 + pr) * NH + h) * 128 + w * 32 + q5;
        mP[idx] = ms;
        LP[idx] = Lrow;
      }
    }
  }
}

// ---------------- combine partials for qt_hi = 31 - pr ----------------
__global__ __launch_bounds__(256) void combine_kernel(const u16* __restrict__ PO, const float* __restrict__ mP,
                                                      const float* __restrict__ LP, u16* __restrict__ Aout){
  const int pr = blockIdx.x;
  const int h  = blockIdx.y;
  const int tid = threadIdx.x;
  const int r  = tid >> 1;             // 0..127
  const int dh = (tid & 1) * 64;
  const int qhi = 31 - pr;
  const int idx0 = ((0 * 16 + pr) * NH + h) * 128 + r;
  const int idx1 = ((1 * 16 + pr) * NH + h) * 128 + r;
  float m0 = mP[idx0], m1 = mP[idx1];
  float L0 = LP[idx0], L1 = LP[idx1];
  float M = fmaxf(m0, m1);
  float a0 = __builtin_amdgcn_exp2f(m0 - M);
  float a1 = __builtin_amdgcn_exp2f(m1 - M);
  float rl = 1.f / (L0 * a0 + L1 * a1);
  const u16* o0 = PO + (size_t)idx0 * 128 + dh;
  const u16* o1 = PO + (size_t)idx1 * 128 + dh;
  u16* dst = Aout + (size_t)(qhi * 128 + r) * QDIM + h * HD + dh;
#pragma unroll
  for (int ch = 0; ch < 8; ch++){
    short8 v0 = *(const short8*)(o0 + ch * 8);
    short8 v1 = *(const short8*)(o1 + ch * 8);
    u32x4 ow;
#pragma unroll
    for (int j = 0; j < 4; j++){
      float e0 = (bf2f((u16)v0[2*j])   * a0 + bf2f((u16)v1[2*j])   * a1) * rl;
      float e1 = (bf2f((u16)v0[2*j+1]) * a0 + bf2f((u16)v1[2*j+1]) * a1) * rl;
      ow[j] = pkr(e0, e1);
    }
    *(u32x4*)(dst + ch * 8) = ow;
  }
}

extern "C" void kernel_launch(void* const* d_in, const int* in_sizes, int n_in,
                              void* d_out, int out_size, void* d_ws, size_t ws_size,
                              hipStream_t stream){
  const float* x  = (const float*)d_in[0];
  const float* Wq = (const float*)d_in[1];
  const float* Wk = (const float*)d_in[2];
  const float* Wv = (const float*)d_in[3];
  const float* Wo = (const float*)d_in[4];

  char* p = (char*)d_ws;
  u16* xb    = (u16*)p; p += (size_t)SEQN * HID * 2;
  u16* Wqkvb = (u16*)p; p += (size_t)QKVS * HID * 2;
  u16* Wob   = (u16*)p; p += (size_t)HID * QDIM * 2;
  u16* QKVb  = (u16*)p; p += (size_t)SEQN * QKVS * 2;
  u16* Ab    = (u16*)p; p += (size_t)SEQN * QDIM * 2;
  u16* VTg   = (u16*)p; p += (size_t)SEQN * KVD * 2;
  u16* PO    = (u16*)p; p += (size_t)2 * 16 * NH * 128 * 128 * 2;   // 16 MB
  float* mP  = (float*)p; p += (size_t)2 * 16 * NH * 128 * 4;
  float* LP  = (float*)p; p += (size_t)2 * 16 * NH * 128 * 4;

  const int totg = G1 + G2 + G3 + G4 + G5;
  cvt5_kernel<<<(totg + 255) / 256, 256, 0, stream>>>(x, Wq, Wk, Wv, Wo, xb, Wqkvb, Wob);

  gemm_kernel<0><<<dim3(SEQN/128, QKVS/128), 256, 0, stream>>>(xb, Wqkvb, QKVb, SEQN, QKVS, HID, QKVS);

  prep_kernel<<<ROPE_BLKS + (SEQN/64) * (KVD/64), 256, 0, stream>>>(QKVb, VTg);

  attn_kernel<<<dim3(16, NH, 2), 256, 0, stream>>>(QKVb, QKVb + QDIM, VTg, Ab, PO, mP, LP);
  combine_kernel<<<dim3(16, NH), 256, 0, stream>>>(PO, mP, LP, Ab);

  gemm_kernel<1><<<dim3(SEQN/128, HID/128), 256, 0, stream>>>(Ab, Wob, d_out, SEQN, HID, QDIM, HID);
}